// Round 1
// baseline (4589.792 us; speedup 1.0000x reference)
//
#include <hip/hip_runtime.h>
#include <math.h>

#define BB 8
#define NN 4096
#define DD 512

#define BM 128
#define BN 128
#define BK 16
#define PAD 4

// C[m,n] = sum_k A[m,k]*B[k,n] (+bias[n]) (+C)
// A row-major, k contiguous, leading dim lda.
// LAYB==0: B element (k,n) at Bp + k*ldb + n   (n contiguous)  -- for x
// LAYB==1: B element (k,n) at Bp + n*ldb + k   (k contiguous)  -- for W[n][k] (A@W^T)
template<int LAYB, bool ACCUM, bool BIAS>
__global__ __launch_bounds__(256, 2)
void gemm_f32(const float* __restrict__ A, const float* __restrict__ Bp,
              const float* __restrict__ bias, float* __restrict__ C,
              int Kk, int lda, int ldb, int ldc,
              long batchB, long batchC)
{
    __shared__ float As[BK][BM + PAD];
    __shared__ float Bs[BK][BN + PAD];

    const int tid = threadIdx.x;
    const int m0 = blockIdx.x * BM;
    const int n0 = blockIdx.y * BN;
    Bp += (long)blockIdx.z * batchB;
    C  += (long)blockIdx.z * batchC;

    // A staging indices: rows ar, ar+64 ; k-chunk ak..ak+3
    const int ar = tid >> 2;
    const int ak = (tid & 3) << 2;
    // B staging indices
    const int bk0 = tid >> 5;          // LAYB==0: k row 0..7 (and +8)
    const int bc0 = (tid & 31) << 2;   // LAYB==0: n col chunk
    const int bi0 = tid >> 2;          // LAYB==1: n row 0..63 (and +64)
    const int bq0 = (tid & 3) << 2;    // LAYB==1: k chunk

    const int tx = tid & 15, ty = tid >> 4;

    float4 pa0, pa1, pb0, pb1;
    {
        const float* Ag = A + (size_t)(m0 + ar) * lda + ak;
        pa0 = *(const float4*)Ag;
        pa1 = *(const float4*)(Ag + (size_t)64 * lda);
        if (LAYB == 0) {
            const float* Bg = Bp + (size_t)bk0 * ldb + n0 + bc0;
            pb0 = *(const float4*)Bg;
            pb1 = *(const float4*)(Bg + (size_t)8 * ldb);
        } else {
            const float* Bg = Bp + (size_t)(n0 + bi0) * ldb + bq0;
            pb0 = *(const float4*)Bg;
            pb1 = *(const float4*)(Bg + (size_t)64 * ldb);
        }
    }

    float acc[8][8];
#pragma unroll
    for (int i = 0; i < 8; ++i)
#pragma unroll
        for (int j = 0; j < 8; ++j) acc[i][j] = 0.0f;

    for (int kt = 0; kt < Kk; kt += BK) {
        __syncthreads();
        // stage to LDS (A transposed)
        As[ak + 0][ar] = pa0.x; As[ak + 1][ar] = pa0.y;
        As[ak + 2][ar] = pa0.z; As[ak + 3][ar] = pa0.w;
        As[ak + 0][ar + 64] = pa1.x; As[ak + 1][ar + 64] = pa1.y;
        As[ak + 2][ar + 64] = pa1.z; As[ak + 3][ar + 64] = pa1.w;
        if (LAYB == 0) {
            *(float4*)&Bs[bk0][bc0]     = pb0;
            *(float4*)&Bs[bk0 + 8][bc0] = pb1;
        } else {
            Bs[bq0 + 0][bi0] = pb0.x; Bs[bq0 + 1][bi0] = pb0.y;
            Bs[bq0 + 2][bi0] = pb0.z; Bs[bq0 + 3][bi0] = pb0.w;
            Bs[bq0 + 0][bi0 + 64] = pb1.x; Bs[bq0 + 1][bi0 + 64] = pb1.y;
            Bs[bq0 + 2][bi0 + 64] = pb1.z; Bs[bq0 + 3][bi0 + 64] = pb1.w;
        }
        __syncthreads();

        if (kt + BK < Kk) {
            const float* Ag = A + (size_t)(m0 + ar) * lda + (kt + BK) + ak;
            pa0 = *(const float4*)Ag;
            pa1 = *(const float4*)(Ag + (size_t)64 * lda);
            if (LAYB == 0) {
                const float* Bg = Bp + (size_t)(kt + BK + bk0) * ldb + n0 + bc0;
                pb0 = *(const float4*)Bg;
                pb1 = *(const float4*)(Bg + (size_t)8 * ldb);
            } else {
                const float* Bg = Bp + (size_t)(n0 + bi0) * ldb + (kt + BK) + bq0;
                pb0 = *(const float4*)Bg;
                pb1 = *(const float4*)(Bg + (size_t)64 * ldb);
            }
        }

#pragma unroll
        for (int kk = 0; kk < BK; ++kk) {
            float4 al = *(const float4*)&As[kk][ty * 4];
            float4 ah = *(const float4*)&As[kk][ty * 4 + 64];
            float4 bl = *(const float4*)&Bs[kk][tx * 4];
            float4 bh = *(const float4*)&Bs[kk][tx * 4 + 64];
            float am[8] = {al.x, al.y, al.z, al.w, ah.x, ah.y, ah.z, ah.w};
            float bv[8] = {bl.x, bl.y, bl.z, bl.w, bh.x, bh.y, bh.z, bh.w};
#pragma unroll
            for (int i = 0; i < 8; ++i)
#pragma unroll
                for (int j = 0; j < 8; ++j)
                    acc[i][j] = fmaf(am[i], bv[j], acc[i][j]);
        }
    }

    float bl0[4] = {0, 0, 0, 0}, bh0[4] = {0, 0, 0, 0};
    if (BIAS) {
        float4 t0 = *(const float4*)&bias[n0 + tx * 4];
        float4 t1 = *(const float4*)&bias[n0 + tx * 4 + 64];
        bl0[0] = t0.x; bl0[1] = t0.y; bl0[2] = t0.z; bl0[3] = t0.w;
        bh0[0] = t1.x; bh0[1] = t1.y; bh0[2] = t1.z; bh0[3] = t1.w;
    }
#pragma unroll
    for (int i = 0; i < 8; ++i) {
        int m = m0 + ty * 4 + (i & 3) + ((i >= 4) ? 64 : 0);
        float* Cr = C + (size_t)m * ldc + n0;
        float v0[4] = {acc[i][0], acc[i][1], acc[i][2], acc[i][3]};
        float v1[4] = {acc[i][4], acc[i][5], acc[i][6], acc[i][7]};
        if (BIAS) {
#pragma unroll
            for (int j = 0; j < 4; ++j) { v0[j] += bl0[j]; v1[j] += bh0[j]; }
        }
        if (ACCUM) {
            float4 o0 = *(const float4*)&Cr[tx * 4];
            float4 o1 = *(const float4*)&Cr[tx * 4 + 64];
            v0[0] += o0.x; v0[1] += o0.y; v0[2] += o0.z; v0[3] += o0.w;
            v1[0] += o1.x; v1[1] += o1.y; v1[2] += o1.z; v1[3] += o1.w;
        }
        float4 s0 = {v0[0], v0[1], v0[2], v0[3]};
        float4 s1 = {v1[0], v1[1], v1[2], v1[3]};
        *(float4*)&Cr[tx * 4]      = s0;
        *(float4*)&Cr[tx * 4 + 64] = s1;
    }
}

// Fused pointwise: gate/cand/mix + LayerNorm + weighted accumulate into out.
__global__ __launch_bounds__(128)
void pw_kernel(const float* __restrict__ x, const float* __restrict__ gp_,
               const float* __restrict__ cp_, const float* __restrict__ lg,
               const float* __restrict__ lb, const float* __restrict__ cmix,
               int c, float* __restrict__ out)
{
    __shared__ float sm[4];
    const int row = blockIdx.x;
    const int tid = threadIdx.x;
    const size_t base = (size_t)row * DD + tid * 4;

    float4 g4 = *(const float4*)(gp_ + base);
    float4 c4 = *(const float4*)(cp_ + base);
    float4 x4 = *(const float4*)(x + base);
    float gv[4] = {g4.x, g4.y, g4.z, g4.w};
    float cv[4] = {c4.x, c4.y, c4.z, c4.w};
    float xv[4] = {x4.x, x4.y, x4.z, x4.w};
    float h[4];
#pragma unroll
    for (int j = 0; j < 4; ++j) {
        float gate = 1.0f / (1.0f + expf(-gv[j]));
        float cand = 0.5f * cv[j] * (1.0f + erff(cv[j] * 0.70710678118654752440f));
        h[j] = gate * cand + (1.0f - gate) * xv[j];
    }

    const int lane = tid & 63, wid = tid >> 6;
    // mean
    float s = h[0] + h[1] + h[2] + h[3];
#pragma unroll
    for (int off = 32; off > 0; off >>= 1) s += __shfl_xor(s, off, 64);
    if (lane == 0) sm[wid] = s;
    __syncthreads();
    float mu = (sm[0] + sm[1]) * (1.0f / 512.0f);
    // var
    float vs = 0.0f;
#pragma unroll
    for (int j = 0; j < 4; ++j) { float d = h[j] - mu; vs += d * d; }
#pragma unroll
    for (int off = 32; off > 0; off >>= 1) vs += __shfl_xor(vs, off, 64);
    if (lane == 0) sm[2 + wid] = vs;
    __syncthreads();
    float var = (sm[2] + sm[3]) * (1.0f / 512.0f);
    float rstd = 1.0f / sqrtf(var + 1e-5f);

    // softmax(channel_mix)[c]
    float m0 = cmix[0], m1 = cmix[1];
    float mx = fmaxf(m0, m1);
    float e0 = expf(m0 - mx), e1 = expf(m1 - mx);
    float w = ((c == 0) ? e0 : e1) / (e0 + e1);

    const int dix = tid * 4;
    float4 lg4 = *(const float4*)(lg + dix);
    float4 lb4 = *(const float4*)(lb + dix);
    float lgv[4] = {lg4.x, lg4.y, lg4.z, lg4.w};
    float lbv[4] = {lb4.x, lb4.y, lb4.z, lb4.w};
    float4 o4 = *(const float4*)(out + base);
    float ov[4] = {o4.x, o4.y, o4.z, o4.w};
#pragma unroll
    for (int j = 0; j < 4; ++j)
        ov[j] += w * ((h[j] - mu) * rstd * lgv[j] + lbv[j]);
    float4 st = {ov[0], ov[1], ov[2], ov[3]};
    *(float4*)(out + base) = st;
}

__global__ __launch_bounds__(128)
void energy_kernel(const float* __restrict__ out, float* __restrict__ energy)
{
    __shared__ float sm[2];
    const int row = blockIdx.x;
    const int tid = threadIdx.x;
    const size_t base = (size_t)row * DD + tid * 4;
    float4 v = *(const float4*)(out + base);
    float s = v.x * v.x + v.y * v.y + v.z * v.z + v.w * v.w;
    const int lane = tid & 63, wid = tid >> 6;
#pragma unroll
    for (int off = 32; off > 0; off >>= 1) s += __shfl_xor(s, off, 64);
    if (lane == 0) sm[wid] = s;
    __syncthreads();
    if (tid == 0) energy[row] = sqrtf(sm[0] + sm[1]);
}

// Per-batch top-k via MSB-first 8-bit radix select; stable lowest-index tie-break
// (matches jax.lax.top_k). Energies are >= 0 so uint bit order == float order.
__global__ __launch_bounds__(1024)
void topk_kernel(const float* __restrict__ energy, const int* __restrict__ kptr,
                 float* __restrict__ mscale)
{
    __shared__ unsigned keys[NN];
    __shared__ int hist[256];
    __shared__ int wsum[16];
    __shared__ unsigned sh_pfx;
    __shared__ int sh_need;

    const int b = blockIdx.x, tid = threadIdx.x;
    const float* e = energy + (size_t)b * NN;
    for (int n = tid; n < NN; n += 1024) keys[n] = __float_as_uint(e[n]);
    const int K = *kptr;
    if (tid == 0) { sh_pfx = 0u; sh_need = K; }
    __syncthreads();

    for (int round = 0; round < 4; ++round) {
        const int shift = 24 - 8 * round;
        if (tid < 256) hist[tid] = 0;
        __syncthreads();
        const unsigned pfx = sh_pfx;
        const unsigned mhi = (round == 0) ? 0u : (0xFFFFFFFFu << (shift + 8));
        for (int n = tid; n < NN; n += 1024) {
            unsigned kv = keys[n];
            if ((kv & mhi) == pfx) atomicAdd(&hist[(kv >> shift) & 255], 1);
        }
        __syncthreads();
        if (tid == 0) {
            int need = sh_need;
            int d = 255;
            for (;; --d) {
                int cct = hist[d];
                if (need <= cct) break;
                need -= cct;
            }
            sh_pfx = pfx | ((unsigned)d << shift);
            sh_need = need;
        }
        __syncthreads();
    }

    const unsigned T = sh_pfx;
    const int need = sh_need;

    const int n0 = tid * 4;
    unsigned kv[4]; int eq[4]; int loc[4];
    int s = 0;
#pragma unroll
    for (int j = 0; j < 4; ++j) {
        kv[j] = keys[n0 + j];
        eq[j] = (kv[j] == T) ? 1 : 0;
        loc[j] = s; s += eq[j];
    }
    const int lane = tid & 63, wid = tid >> 6;
    int v = s;
#pragma unroll
    for (int off = 1; off < 64; off <<= 1) {
        int u = __shfl_up(v, off, 64);
        if (lane >= off) v += u;
    }
    if (lane == 63) wsum[wid] = v;
    __syncthreads();
    if (tid == 0) {
        int acc = 0;
        for (int w2 = 0; w2 < 16; ++w2) { int t = wsum[w2]; wsum[w2] = acc; acc += t; }
    }
    __syncthreads();
    const int base = wsum[wid] + (v - s);
    const float scale = (float)(4096.0 / (double)K);
#pragma unroll
    for (int j = 0; j < 4; ++j) {
        bool sel = (kv[j] > T) || (eq[j] && (base + loc[j]) < need);
        mscale[(size_t)b * NN + n0 + j] = sel ? scale : 0.0f;
    }
}

__global__ __launch_bounds__(128)
void mask_kernel(float* __restrict__ out, const float* __restrict__ mscale)
{
    const int row = blockIdx.x;
    const int tid = threadIdx.x;
    const size_t base = (size_t)row * DD + tid * 4;
    const float sc = mscale[row];
    float4 v = *(const float4*)(out + base);
    v.x *= sc; v.y *= sc; v.z *= sc; v.w *= sc;
    *(float4*)(out + base) = v;
}

extern "C" void kernel_launch(void* const* d_in, const int* in_sizes, int n_in,
                              void* d_out, int out_size, void* d_ws, size_t ws_size,
                              hipStream_t stream)
{
    const float* x      = (const float*)d_in[0];
    const float* net    = (const float*)d_in[1];
    const float* gate_w = (const float*)d_in[2];
    const float* gate_b = (const float*)d_in[3];
    const float* cand_w = (const float*)d_in[4];
    const float* cand_b = (const float*)d_in[5];
    const float* ln_g   = (const float*)d_in[6];
    const float* ln_b   = (const float*)d_in[7];
    const float* cmix   = (const float*)d_in[8];
    const int*   kptr   = (const int*)d_in[9];
    float* out = (float*)d_out;
    float* ws  = (float*)d_ws;

    const size_t ROWS = (size_t)BB * NN;          // 32768
    const size_t PLANE = ROWS * DD;               // 16,777,216 floats
    float* inter  = ws;
    float* candp  = ws + PLANE;
    float* gatep  = ws + 2 * PLANE;
    float* energy = ws + 3 * PLANE;
    float* mscalep = energy + ROWS;

    hipMemsetAsync(d_out, 0, PLANE * sizeof(float), stream);

    for (int c = 0; c < 2; ++c) {
        // interaction[b] = net[c] @ x[b]
        gemm_f32<0, false, false><<<dim3(NN / BM, DD / BN, BB), 256, 0, stream>>>(
            net + (size_t)c * NN * NN, x, nullptr, inter,
            NN, NN, DD, DD, (long)NN * DD, (long)NN * DD);
        // cand_pre = inter @ cand_w[c]^T + cand_b[c]
        gemm_f32<1, false, true><<<dim3(ROWS / BM, DD / BN, 1), 256, 0, stream>>>(
            inter, cand_w + (size_t)c * DD * DD, cand_b + (size_t)c * DD, candp,
            DD, DD, DD, DD, 0, 0);
        // gate_pre = x @ gw[c][:, :D]^T + gate_b[c]
        gemm_f32<1, false, true><<<dim3(ROWS / BM, DD / BN, 1), 256, 0, stream>>>(
            x, gate_w + (size_t)c * DD * 2 * DD, gate_b + (size_t)c * DD, gatep,
            DD, DD, 2 * DD, DD, 0, 0);
        // gate_pre += inter @ gw[c][:, D:]^T
        gemm_f32<1, true, false><<<dim3(ROWS / BM, DD / BN, 1), 256, 0, stream>>>(
            inter, gate_w + (size_t)c * DD * 2 * DD + DD, nullptr, gatep,
            DD, DD, 2 * DD, DD, 0, 0);
        // pointwise + LN + accumulate
        pw_kernel<<<(int)ROWS, 128, 0, stream>>>(
            x, gatep, candp, ln_g + (size_t)c * DD, ln_b + (size_t)c * DD, cmix, c, out);
    }

    energy_kernel<<<(int)ROWS, 128, 0, stream>>>(out, energy);
    topk_kernel<<<BB, 1024, 0, stream>>>(energy, kptr, mscalep);
    mask_kernel<<<(int)ROWS, 128, 0, stream>>>(out, mscalep);
}

// Round 2
// 2657.504 us; speedup vs baseline: 1.7271x; 1.7271x over previous
//
#include <hip/hip_runtime.h>
#include <hip/hip_bf16.h>
#include <math.h>

#define BB 8
#define NN 4096
#define DD 512

#define BM 128
#define BN 128
#define BK 16
#define PAD 4

typedef short bf16x8 __attribute__((ext_vector_type(8)));
typedef float f32x4 __attribute__((ext_vector_type(4)));

#define AS1 __attribute__((address_space(1)))
#define AS3 __attribute__((address_space(3)))

// async global->LDS, 16B per lane; LDS dest = wave-uniform base + lane*16
__device__ __forceinline__ void gload_lds16(const void* g, void* l) {
    __builtin_amdgcn_global_load_lds((const AS1 unsigned int*)g,
                                     (AS3 unsigned int*)l, 16, 0, 0);
}

__device__ __forceinline__ void split_bf16(float v, unsigned short& h, unsigned short& l) {
    __hip_bfloat16 bh = __float2bfloat16(v);         // RNE
    float hf = __bfloat162float(bh);
    __hip_bfloat16 bl = __float2bfloat16(v - hf);
    h = *reinterpret_cast<unsigned short*>(&bh);
    l = *reinterpret_cast<unsigned short*>(&bl);
}

// ---------------- conversion: net[c] fp32 [m][k] -> hi/lo bf16 planes (same layout)
__global__ __launch_bounds__(256)
void conv_split(const float* __restrict__ src, unsigned short* __restrict__ hi,
                unsigned short* __restrict__ lo)
{
    const size_t i = (size_t)blockIdx.x * 256 + threadIdx.x;   // float4 index
    float4 v = ((const float4*)src)[i];
    ushort4 h, l;
    split_bf16(v.x, h.x, l.x);
    split_bf16(v.y, h.y, l.y);
    split_bf16(v.z, h.z, l.z);
    split_bf16(v.w, h.w, l.w);
    ((ushort4*)hi)[i] = h;
    ((ushort4*)lo)[i] = l;
}

// ---------------- conversion + transpose: x fp32 [b][n][d] -> xT hi/lo bf16 [b][d][n]
__global__ __launch_bounds__(256)
void conv_xT(const float* __restrict__ x, unsigned short* __restrict__ th,
             unsigned short* __restrict__ tl)
{
    __shared__ unsigned short Th[64][65];
    __shared__ unsigned short Tl[64][65];
    const int n0 = blockIdx.x * 64, d0 = blockIdx.y * 64, b = blockIdx.z;
    const int t = threadIdx.x;
    const int r = t >> 4, c4 = (t & 15) * 4;
#pragma unroll
    for (int i = 0; i < 4; ++i) {
        int row = r + i * 16;
        float4 v = *(const float4*)(x + ((size_t)b * NN + n0 + row) * DD + d0 + c4);
        split_bf16(v.x, Th[row][c4 + 0], Tl[row][c4 + 0]);
        split_bf16(v.y, Th[row][c4 + 1], Tl[row][c4 + 1]);
        split_bf16(v.z, Th[row][c4 + 2], Tl[row][c4 + 2]);
        split_bf16(v.w, Th[row][c4 + 3], Tl[row][c4 + 3]);
    }
    __syncthreads();
    const int od = t >> 2;            // 0..63 output d-row
    const int on0 = (t & 3) * 16;     // 0,16,32,48 n-col group
    unsigned short hb[16], lb[16];
#pragma unroll
    for (int j = 0; j < 16; ++j) { hb[j] = Th[on0 + j][od]; lb[j] = Tl[on0 + j][od]; }
    const size_t obase = ((size_t)b * DD + d0 + od) * (size_t)NN + n0 + on0;
#pragma unroll
    for (int q = 0; q < 4; ++q) {
        ushort4 hv = {hb[q * 4 + 0], hb[q * 4 + 1], hb[q * 4 + 2], hb[q * 4 + 3]};
        ushort4 lv = {lb[q * 4 + 0], lb[q * 4 + 1], lb[q * 4 + 2], lb[q * 4 + 3]};
        *(ushort4*)(th + obase + q * 4) = hv;
        *(ushort4*)(tl + obase + q * 4) = lv;
    }
}

// ---------------- split-3 bf16 MFMA GEMM: inter[b][m][d] = net[m][k] * x[b][k][d]
// A planes: [4096][4096] bf16 (k contig). B planes: [b][512(d)][4096(k)] bf16 (k contig).
// Tile 128x128, 4 waves of 64x64, 16x16x32 bf16 MFMA, 3 products per tile.
// LDS tiles [row][k] 128x32 bf16 with 16B-chunk XOR swizzle slot = kc ^ ((r + r/4)&3).
__global__ __launch_bounds__(256, 2)
void gemm3bf(const unsigned short* __restrict__ Ah, const unsigned short* __restrict__ Al,
             const unsigned short* __restrict__ Bh, const unsigned short* __restrict__ Bl,
             float* __restrict__ C)
{
    __shared__ alignas(16) unsigned short sAh[128 * 32];
    __shared__ alignas(16) unsigned short sAl[128 * 32];
    __shared__ alignas(16) unsigned short sBh[128 * 32];
    __shared__ alignas(16) unsigned short sBl[128 * 32];

    const int tid = threadIdx.x;
    const int lane = tid & 63;
    const int w = tid >> 6;

    const int n0 = blockIdx.x * 128;   // d tile (512/128 = 4)
    const int b  = blockIdx.y;         // batch
    const int m0 = blockIdx.z * 128;   // agent tile (4096/128 = 32)

    Bh += (size_t)b * DD * NN;
    Bl += (size_t)b * DD * NN;
    C  += (size_t)b * NN * DD;

    // staging: wave w fills chunks c0,c1 (1 KiB each) of each of the 4 tiles
    const int c0 = w * 2, c1 = c0 + 1;
    const int u2 = lane >> 2;                       // row within chunk (0..15)
    const int sst = (u2 + (u2 >> 2)) & 3;           // swizzle of this row
    const int kc = (lane & 3) ^ sst;                // global 16B chunk this lane fetches
    const size_t gA0 = (size_t)(m0 + c0 * 16 + u2) * NN + kc * 8;
    const size_t gA1 = (size_t)(m0 + c1 * 16 + u2) * NN + kc * 8;
    const size_t gB0 = (size_t)(n0 + c0 * 16 + u2) * NN + kc * 8;
    const size_t gB1 = (size_t)(n0 + c1 * 16 + u2) * NN + kc * 8;
    unsigned short* lAh0 = sAh + c0 * 512; unsigned short* lAh1 = sAh + c1 * 512;
    unsigned short* lAl0 = sAl + c0 * 512; unsigned short* lAl1 = sAl + c1 * 512;
    unsigned short* lBh0 = sBh + c0 * 512; unsigned short* lBh1 = sBh + c1 * 512;
    unsigned short* lBl0 = sBl + c0 * 512; unsigned short* lBl1 = sBl + c1 * 512;

    // fragment read byte offsets
    const int wm = (w & 1) * 64, wn = (w >> 1) * 64;
    const int fr = lane & 15;
    const int sf = (fr + (fr >> 2)) & 3;
    const int fslot = ((lane >> 4) ^ sf) * 16;
    int offA[4], offB[4];
#pragma unroll
    for (int i = 0; i < 4; ++i) {
        offA[i] = (wm + i * 16 + fr) * 64 + fslot;
        offB[i] = (wn + i * 16 + fr) * 64 + fslot;
    }

    f32x4 acc[4][4] = {};

    for (int kt = 0; kt < NN; kt += 32) {
        __syncthreads();
        gload_lds16(Ah + gA0 + kt, lAh0);
        gload_lds16(Ah + gA1 + kt, lAh1);
        gload_lds16(Al + gA0 + kt, lAl0);
        gload_lds16(Al + gA1 + kt, lAl1);
        gload_lds16(Bh + gB0 + kt, lBh0);
        gload_lds16(Bh + gB1 + kt, lBh1);
        gload_lds16(Bl + gB0 + kt, lBl0);
        gload_lds16(Bl + gB1 + kt, lBl1);
        asm volatile("s_waitcnt vmcnt(0)" ::: "memory");
        __syncthreads();

        bf16x8 ah[4], al[4], bh[4], bl[4];
#pragma unroll
        for (int i = 0; i < 4; ++i) {
            ah[i] = *(const bf16x8*)((const char*)sAh + offA[i]);
            al[i] = *(const bf16x8*)((const char*)sAl + offA[i]);
            bh[i] = *(const bf16x8*)((const char*)sBh + offB[i]);
            bl[i] = *(const bf16x8*)((const char*)sBl + offB[i]);
        }
#pragma unroll
        for (int mi = 0; mi < 4; ++mi)
#pragma unroll
            for (int ni = 0; ni < 4; ++ni) {
                acc[mi][ni] = __builtin_amdgcn_mfma_f32_16x16x32_bf16(al[mi], bh[ni], acc[mi][ni], 0, 0, 0);
                acc[mi][ni] = __builtin_amdgcn_mfma_f32_16x16x32_bf16(ah[mi], bl[ni], acc[mi][ni], 0, 0, 0);
                acc[mi][ni] = __builtin_amdgcn_mfma_f32_16x16x32_bf16(ah[mi], bh[ni], acc[mi][ni], 0, 0, 0);
            }
    }

    // epilogue: C/D layout col=lane&15, row=(lane>>4)*4+r
    const int erow = (lane >> 4) * 4;
#pragma unroll
    for (int mi = 0; mi < 4; ++mi)
#pragma unroll
        for (int ni = 0; ni < 4; ++ni) {
            const int r0 = m0 + wm + mi * 16 + erow;
            const int col = n0 + wn + ni * 16 + fr;
#pragma unroll
            for (int r = 0; r < 4; ++r)
                C[(size_t)(r0 + r) * DD + col] = acc[mi][ni][r];
        }
}

// ---------------- fp32 vector GEMM (unchanged; used for cand/gate) ----------------
template<int LAYB, bool ACCUM, bool BIAS>
__global__ __launch_bounds__(256, 2)
void gemm_f32(const float* __restrict__ A, const float* __restrict__ Bp,
              const float* __restrict__ bias, float* __restrict__ C,
              int Kk, int lda, int ldb, int ldc,
              long batchB, long batchC)
{
    __shared__ float As[BK][BM + PAD];
    __shared__ float Bs[BK][BN + PAD];

    const int tid = threadIdx.x;
    const int m0 = blockIdx.x * BM;
    const int n0 = blockIdx.y * BN;
    Bp += (long)blockIdx.z * batchB;
    C  += (long)blockIdx.z * batchC;

    const int ar = tid >> 2;
    const int ak = (tid & 3) << 2;
    const int bk0 = tid >> 5;
    const int bc0 = (tid & 31) << 2;
    const int bi0 = tid >> 2;
    const int bq0 = (tid & 3) << 2;

    const int tx = tid & 15, ty = tid >> 4;

    float4 pa0, pa1, pb0, pb1;
    {
        const float* Ag = A + (size_t)(m0 + ar) * lda + ak;
        pa0 = *(const float4*)Ag;
        pa1 = *(const float4*)(Ag + (size_t)64 * lda);
        if (LAYB == 0) {
            const float* Bg = Bp + (size_t)bk0 * ldb + n0 + bc0;
            pb0 = *(const float4*)Bg;
            pb1 = *(const float4*)(Bg + (size_t)8 * ldb);
        } else {
            const float* Bg = Bp + (size_t)(n0 + bi0) * ldb + bq0;
            pb0 = *(const float4*)Bg;
            pb1 = *(const float4*)(Bg + (size_t)64 * ldb);
        }
    }

    float acc[8][8];
#pragma unroll
    for (int i = 0; i < 8; ++i)
#pragma unroll
        for (int j = 0; j < 8; ++j) acc[i][j] = 0.0f;

    for (int kt = 0; kt < Kk; kt += BK) {
        __syncthreads();
        As[ak + 0][ar] = pa0.x; As[ak + 1][ar] = pa0.y;
        As[ak + 2][ar] = pa0.z; As[ak + 3][ar] = pa0.w;
        As[ak + 0][ar + 64] = pa1.x; As[ak + 1][ar + 64] = pa1.y;
        As[ak + 2][ar + 64] = pa1.z; As[ak + 3][ar + 64] = pa1.w;
        if (LAYB == 0) {
            *(float4*)&Bs[bk0][bc0]     = pb0;
            *(float4*)&Bs[bk0 + 8][bc0] = pb1;
        } else {
            Bs[bq0 + 0][bi0] = pb0.x; Bs[bq0 + 1][bi0] = pb0.y;
            Bs[bq0 + 2][bi0] = pb0.z; Bs[bq0 + 3][bi0] = pb0.w;
            Bs[bq0 + 0][bi0 + 64] = pb1.x; Bs[bq0 + 1][bi0 + 64] = pb1.y;
            Bs[bq0 + 2][bi0 + 64] = pb1.z; Bs[bq0 + 3][bi0 + 64] = pb1.w;
        }
        __syncthreads();

        if (kt + BK < Kk) {
            const float* Ag = A + (size_t)(m0 + ar) * lda + (kt + BK) + ak;
            pa0 = *(const float4*)Ag;
            pa1 = *(const float4*)(Ag + (size_t)64 * lda);
            if (LAYB == 0) {
                const float* Bg = Bp + (size_t)(kt + BK + bk0) * ldb + n0 + bc0;
                pb0 = *(const float4*)Bg;
                pb1 = *(const float4*)(Bg + (size_t)8 * ldb);
            } else {
                const float* Bg = Bp + (size_t)(n0 + bi0) * ldb + (kt + BK) + bq0;
                pb0 = *(const float4*)Bg;
                pb1 = *(const float4*)(Bg + (size_t)64 * ldb);
            }
        }

#pragma unroll
        for (int kk = 0; kk < BK; ++kk) {
            float4 al = *(const float4*)&As[kk][ty * 4];
            float4 ah = *(const float4*)&As[kk][ty * 4 + 64];
            float4 bl = *(const float4*)&Bs[kk][tx * 4];
            float4 bh = *(const float4*)&Bs[kk][tx * 4 + 64];
            float am[8] = {al.x, al.y, al.z, al.w, ah.x, ah.y, ah.z, ah.w};
            float bv[8] = {bl.x, bl.y, bl.z, bl.w, bh.x, bh.y, bh.z, bh.w};
#pragma unroll
            for (int i = 0; i < 8; ++i)
#pragma unroll
                for (int j = 0; j < 8; ++j)
                    acc[i][j] = fmaf(am[i], bv[j], acc[i][j]);
        }
    }

    float bl0[4] = {0, 0, 0, 0}, bh0[4] = {0, 0, 0, 0};
    if (BIAS) {
        float4 t0 = *(const float4*)&bias[n0 + tx * 4];
        float4 t1 = *(const float4*)&bias[n0 + tx * 4 + 64];
        bl0[0] = t0.x; bl0[1] = t0.y; bl0[2] = t0.z; bl0[3] = t0.w;
        bh0[0] = t1.x; bh0[1] = t1.y; bh0[2] = t1.z; bh0[3] = t1.w;
    }
#pragma unroll
    for (int i = 0; i < 8; ++i) {
        int m = m0 + ty * 4 + (i & 3) + ((i >= 4) ? 64 : 0);
        float* Cr = C + (size_t)m * ldc + n0;
        float v0[4] = {acc[i][0], acc[i][1], acc[i][2], acc[i][3]};
        float v1[4] = {acc[i][4], acc[i][5], acc[i][6], acc[i][7]};
        if (BIAS) {
#pragma unroll
            for (int j = 0; j < 4; ++j) { v0[j] += bl0[j]; v1[j] += bh0[j]; }
        }
        if (ACCUM) {
            float4 o0 = *(const float4*)&Cr[tx * 4];
            float4 o1 = *(const float4*)&Cr[tx * 4 + 64];
            v0[0] += o0.x; v0[1] += o0.y; v0[2] += o0.z; v0[3] += o0.w;
            v1[0] += o1.x; v1[1] += o1.y; v1[2] += o1.z; v1[3] += o1.w;
        }
        float4 s0 = {v0[0], v0[1], v0[2], v0[3]};
        float4 s1 = {v1[0], v1[1], v1[2], v1[3]};
        *(float4*)&Cr[tx * 4]      = s0;
        *(float4*)&Cr[tx * 4 + 64] = s1;
    }
}

// ---------------- fused pointwise + LN + weighted accumulate ----------------
__global__ __launch_bounds__(128)
void pw_kernel(const float* __restrict__ x, const float* __restrict__ gp_,
               const float* __restrict__ cp_, const float* __restrict__ lg,
               const float* __restrict__ lb, const float* __restrict__ cmix,
               int c, float* __restrict__ out)
{
    __shared__ float sm[4];
    const int row = blockIdx.x;
    const int tid = threadIdx.x;
    const size_t base = (size_t)row * DD + tid * 4;

    float4 g4 = *(const float4*)(gp_ + base);
    float4 c4 = *(const float4*)(cp_ + base);
    float4 x4 = *(const float4*)(x + base);
    float gv[4] = {g4.x, g4.y, g4.z, g4.w};
    float cv[4] = {c4.x, c4.y, c4.z, c4.w};
    float xv[4] = {x4.x, x4.y, x4.z, x4.w};
    float h[4];
#pragma unroll
    for (int j = 0; j < 4; ++j) {
        float gate = 1.0f / (1.0f + expf(-gv[j]));
        float cand = 0.5f * cv[j] * (1.0f + erff(cv[j] * 0.70710678118654752440f));
        h[j] = gate * cand + (1.0f - gate) * xv[j];
    }

    const int lane = tid & 63, wid = tid >> 6;
    float s = h[0] + h[1] + h[2] + h[3];
#pragma unroll
    for (int off = 32; off > 0; off >>= 1) s += __shfl_xor(s, off, 64);
    if (lane == 0) sm[wid] = s;
    __syncthreads();
    float mu = (sm[0] + sm[1]) * (1.0f / 512.0f);
    float vs = 0.0f;
#pragma unroll
    for (int j = 0; j < 4; ++j) { float d = h[j] - mu; vs += d * d; }
#pragma unroll
    for (int off = 32; off > 0; off >>= 1) vs += __shfl_xor(vs, off, 64);
    if (lane == 0) sm[2 + wid] = vs;
    __syncthreads();
    float var = (sm[2] + sm[3]) * (1.0f / 512.0f);
    float rstd = 1.0f / sqrtf(var + 1e-5f);

    float m0 = cmix[0], m1 = cmix[1];
    float mx = fmaxf(m0, m1);
    float e0 = expf(m0 - mx), e1 = expf(m1 - mx);
    float w = ((c == 0) ? e0 : e1) / (e0 + e1);

    const int dix = tid * 4;
    float4 lg4 = *(const float4*)(lg + dix);
    float4 lb4 = *(const float4*)(lb + dix);
    float lgv[4] = {lg4.x, lg4.y, lg4.z, lg4.w};
    float lbv[4] = {lb4.x, lb4.y, lb4.z, lb4.w};
    float4 o4 = *(const float4*)(out + base);
    float ov[4] = {o4.x, o4.y, o4.z, o4.w};
#pragma unroll
    for (int j = 0; j < 4; ++j)
        ov[j] += w * ((h[j] - mu) * rstd * lgv[j] + lbv[j]);
    float4 st = {ov[0], ov[1], ov[2], ov[3]};
    *(float4*)(out + base) = st;
}

__global__ __launch_bounds__(128)
void energy_kernel(const float* __restrict__ out, float* __restrict__ energy)
{
    __shared__ float sm[2];
    const int row = blockIdx.x;
    const int tid = threadIdx.x;
    const size_t base = (size_t)row * DD + tid * 4;
    float4 v = *(const float4*)(out + base);
    float s = v.x * v.x + v.y * v.y + v.z * v.z + v.w * v.w;
    const int lane = tid & 63, wid = tid >> 6;
#pragma unroll
    for (int off = 32; off > 0; off >>= 1) s += __shfl_xor(s, off, 64);
    if (lane == 0) sm[wid] = s;
    __syncthreads();
    if (tid == 0) energy[row] = sqrtf(sm[0] + sm[1]);
}

__global__ __launch_bounds__(1024)
void topk_kernel(const float* __restrict__ energy, const int* __restrict__ kptr,
                 float* __restrict__ mscale)
{
    __shared__ unsigned keys[NN];
    __shared__ int hist[256];
    __shared__ int wsum[16];
    __shared__ unsigned sh_pfx;
    __shared__ int sh_need;

    const int b = blockIdx.x, tid = threadIdx.x;
    const float* e = energy + (size_t)b * NN;
    for (int n = tid; n < NN; n += 1024) keys[n] = __float_as_uint(e[n]);
    const int K = *kptr;
    if (tid == 0) { sh_pfx = 0u; sh_need = K; }
    __syncthreads();

    for (int round = 0; round < 4; ++round) {
        const int shift = 24 - 8 * round;
        if (tid < 256) hist[tid] = 0;
        __syncthreads();
        const unsigned pfx = sh_pfx;
        const unsigned mhi = (round == 0) ? 0u : (0xFFFFFFFFu << (shift + 8));
        for (int n = tid; n < NN; n += 1024) {
            unsigned kv = keys[n];
            if ((kv & mhi) == pfx) atomicAdd(&hist[(kv >> shift) & 255], 1);
        }
        __syncthreads();
        if (tid == 0) {
            int need = sh_need;
            int d = 255;
            for (;; --d) {
                int cct = hist[d];
                if (need <= cct) break;
                need -= cct;
            }
            sh_pfx = pfx | ((unsigned)d << shift);
            sh_need = need;
        }
        __syncthreads();
    }

    const unsigned T = sh_pfx;
    const int need = sh_need;

    const int n0 = tid * 4;
    unsigned kv[4]; int eq[4]; int loc[4];
    int s = 0;
#pragma unroll
    for (int j = 0; j < 4; ++j) {
        kv[j] = keys[n0 + j];
        eq[j] = (kv[j] == T) ? 1 : 0;
        loc[j] = s; s += eq[j];
    }
    const int lane = tid & 63, wid = tid >> 6;
    int v = s;
#pragma unroll
    for (int off = 1; off < 64; off <<= 1) {
        int u = __shfl_up(v, off, 64);
        if (lane >= off) v += u;
    }
    if (lane == 63) wsum[wid] = v;
    __syncthreads();
    if (tid == 0) {
        int acc = 0;
        for (int w2 = 0; w2 < 16; ++w2) { int t = wsum[w2]; wsum[w2] = acc; acc += t; }
    }
    __syncthreads();
    const int base = wsum[wid] + (v - s);
    const float scale = (float)(4096.0 / (double)K);
#pragma unroll
    for (int j = 0; j < 4; ++j) {
        bool sel = (kv[j] > T) || (eq[j] && (base + loc[j]) < need);
        mscale[(size_t)b * NN + n0 + j] = sel ? scale : 0.0f;
    }
}

__global__ __launch_bounds__(128)
void mask_kernel(float* __restrict__ out, const float* __restrict__ mscale)
{
    const int row = blockIdx.x;
    const int tid = threadIdx.x;
    const size_t base = (size_t)row * DD + tid * 4;
    const float sc = mscale[row];
    float4 v = *(const float4*)(out + base);
    v.x *= sc; v.y *= sc; v.z *= sc; v.w *= sc;
    *(float4*)(out + base) = v;
}

extern "C" void kernel_launch(void* const* d_in, const int* in_sizes, int n_in,
                              void* d_out, int out_size, void* d_ws, size_t ws_size,
                              hipStream_t stream)
{
    const float* x      = (const float*)d_in[0];
    const float* net    = (const float*)d_in[1];
    const float* gate_w = (const float*)d_in[2];
    const float* gate_b = (const float*)d_in[3];
    const float* cand_w = (const float*)d_in[4];
    const float* cand_b = (const float*)d_in[5];
    const float* ln_g   = (const float*)d_in[6];
    const float* ln_b   = (const float*)d_in[7];
    const float* cmix   = (const float*)d_in[8];
    const int*   kptr   = (const int*)d_in[9];
    float* out = (float*)d_out;

    const size_t ROWS  = (size_t)BB * NN;     // 32768
    const size_t PLANE = ROWS * DD;           // 16,777,216
    const size_t HALF  = PLANE / 2;           // slab of 16384 rows

    // workspace carve (total 201.6 MB, same as round 1):
    //   xTh, xTl : 33.55 MB each (bf16 [b][d][n] planes)
    //   BUF1     : 67.11 MB — net hi/lo planes, later aliased by candp/gatep slabs
    //   inter    : 67.11 MB fp32
    //   energy, mscale
    char* p = (char*)d_ws;
    unsigned short* xTh = (unsigned short*)p;  p += PLANE * 2;
    unsigned short* xTl = (unsigned short*)p;  p += PLANE * 2;
    unsigned short* nh  = (unsigned short*)p;
    unsigned short* nl  = nh + (size_t)NN * NN;
    float* candp = (float*)nh;                 // slab alias (33.55 MB)
    float* gatep = candp + HALF;               // slab alias (33.55 MB)
    p += (size_t)NN * NN * 2 * 2;              // 67.11 MB
    float* inter = (float*)p;                  p += PLANE * 4;
    float* energy = (float*)p;                 p += ROWS * 4;
    float* mscalep = (float*)p;

    hipMemsetAsync(d_out, 0, PLANE * sizeof(float), stream);

    // x -> transposed hi/lo bf16 planes (once)
    conv_xT<<<dim3(NN / 64, DD / 64, BB), 256, 0, stream>>>(x, xTh, xTl);

    for (int c = 0; c < 2; ++c) {
        // net[c] -> hi/lo planes
        conv_split<<<(NN * NN / 4) / 256, 256, 0, stream>>>(net + (size_t)c * NN * NN, nh, nl);

        // interaction[b] = net[c] @ x[b]  (split-3 bf16 MFMA)
        gemm3bf<<<dim3(DD / 128, BB, NN / 128), 256, 0, stream>>>(nh, nl, xTh, xTl, inter);

        // cand/gate GEMMs + pointwise, in two row-slabs (aliases BUF1)
        for (int s = 0; s < 2; ++s) {
            const size_t roff = (size_t)s * HALF;
            gemm_f32<1, false, true><<<dim3(128, 4, 1), 256, 0, stream>>>(
                inter + roff, cand_w + (size_t)c * DD * DD, cand_b + (size_t)c * DD, candp,
                DD, DD, DD, DD, 0, 0);
            gemm_f32<1, false, true><<<dim3(128, 4, 1), 256, 0, stream>>>(
                x + roff, gate_w + (size_t)c * DD * 2 * DD, gate_b + (size_t)c * DD, gatep,
                DD, DD, 2 * DD, DD, 0, 0);
            gemm_f32<1, true, false><<<dim3(128, 4, 1), 256, 0, stream>>>(
                inter + roff, gate_w + (size_t)c * DD * 2 * DD + DD, nullptr, gatep,
                DD, DD, 2 * DD, DD, 0, 0);
            pw_kernel<<<(int)(ROWS / 2), 128, 0, stream>>>(
                x + roff, gatep, candp, ln_g + (size_t)c * DD, ln_b + (size_t)c * DD,
                cmix, c, out + roff);
        }
    }

    energy_kernel<<<(int)ROWS, 128, 0, stream>>>(out, energy);
    topk_kernel<<<BB, 1024, 0, stream>>>(energy, kptr, mscalep);
    mask_kernel<<<(int)ROWS, 128, 0, stream>>>(out, mscalep);
}

// Round 3
// 1727.810 us; speedup vs baseline: 2.6564x; 1.5381x over previous
//
#include <hip/hip_runtime.h>
#include <hip/hip_bf16.h>
#include <math.h>

#define BB 8
#define NN 4096
#define DD 512
#define SLAB 2048                  // agents per slab
#define SROWS (BB * SLAB)          // 16384 rows per slab

typedef short bf16x8 __attribute__((ext_vector_type(8)));
typedef float f32x4 __attribute__((ext_vector_type(4)));

#define AS1 __attribute__((address_space(1)))
#define AS3 __attribute__((address_space(3)))

__device__ __forceinline__ void gload_lds16(const void* g, void* l) {
    __builtin_amdgcn_global_load_lds((const AS1 unsigned int*)g,
                                     (AS3 unsigned int*)l, 16, 0, 0);
}

__device__ __forceinline__ void split_bf16(float v, unsigned short& h, unsigned short& l) {
    __hip_bfloat16 bh = __float2bfloat16(v);         // RNE
    float hf = __bfloat162float(bh);
    __hip_bfloat16 bl = __float2bfloat16(v - hf);
    h = *reinterpret_cast<unsigned short*>(&bh);
    l = *reinterpret_cast<unsigned short*>(&bl);
}

// ---------------- generic contiguous split conv (used for net slabs)
__global__ __launch_bounds__(256)
void conv_split(const float* __restrict__ src, unsigned short* __restrict__ hi,
                unsigned short* __restrict__ lo)
{
    const size_t i = (size_t)blockIdx.x * 256 + threadIdx.x;   // float4 index
    float4 v = ((const float4*)src)[i];
    ushort4 h, l;
    split_bf16(v.x, h.x, l.x);
    split_bf16(v.y, h.y, l.y);
    split_bf16(v.z, h.z, l.z);
    split_bf16(v.w, h.w, l.w);
    ((ushort4*)hi)[i] = h;
    ((ushort4*)lo)[i] = l;
}

// ---------------- fused weight split: cand_w[c] + gate_w[c] x-part + inter-part
__global__ __launch_bounds__(256)
void conv_w3(const float* __restrict__ cw, const float* __restrict__ gw,
             unsigned short* __restrict__ cwh, unsigned short* __restrict__ cwl,
             unsigned short* __restrict__ gxh, unsigned short* __restrict__ gxl,
             unsigned short* __restrict__ gih, unsigned short* __restrict__ gil)
{
    const int blk = blockIdx.x;                 // 0..767
    const int i = (blk & 255) * 256 + threadIdx.x;   // 0..65535 float4 index
    const int n = i >> 7, kq = (i & 127) * 4;
    const float* src;
    unsigned short *oh, *ol;
    if (blk < 256)      { src = cw + (size_t)n * 512 + kq;        oh = cwh; ol = cwl; }
    else if (blk < 512) { src = gw + (size_t)n * 1024 + kq;       oh = gxh; ol = gxl; }
    else                { src = gw + (size_t)n * 1024 + 512 + kq; oh = gih; ol = gil; }
    float4 v = *(const float4*)src;
    ushort4 h, l;
    split_bf16(v.x, h.x, l.x);
    split_bf16(v.y, h.y, l.y);
    split_bf16(v.z, h.z, l.z);
    split_bf16(v.w, h.w, l.w);
    *(ushort4*)(oh + (size_t)n * 512 + kq) = h;
    *(ushort4*)(ol + (size_t)n * 512 + kq) = l;
}

// ---------------- x slab rows -> split planes [16384][512]
__global__ __launch_bounds__(256)
void conv_xs(const float* __restrict__ x, int nbase,
             unsigned short* __restrict__ hi, unsigned short* __restrict__ lo)
{
    const size_t i = (size_t)blockIdx.x * 256 + threadIdx.x;   // float4 idx, 2,097,152
    const int r = (int)(i >> 7), kq = (int)(i & 127) * 4;
    const int b = r >> 11, ii = r & (SLAB - 1);
    float4 v = *(const float4*)(x + ((size_t)(b << 12) + nbase + ii) * DD + kq);
    ushort4 h, l;
    split_bf16(v.x, h.x, l.x);
    split_bf16(v.y, h.y, l.y);
    split_bf16(v.z, h.z, l.z);
    split_bf16(v.w, h.w, l.w);
    *(ushort4*)(hi + (size_t)r * DD + kq) = h;
    *(ushort4*)(lo + (size_t)r * DD + kq) = l;
}

// ---------------- conversion + transpose: x fp32 [b][n][d] -> xT hi/lo bf16 [b][d][n]
__global__ __launch_bounds__(256)
void conv_xT(const float* __restrict__ x, unsigned short* __restrict__ th,
             unsigned short* __restrict__ tl)
{
    __shared__ unsigned short Th[64][65];
    __shared__ unsigned short Tl[64][65];
    const int n0 = blockIdx.x * 64, d0 = blockIdx.y * 64, b = blockIdx.z;
    const int t = threadIdx.x;
    const int r = t >> 4, c4 = (t & 15) * 4;
#pragma unroll
    for (int i = 0; i < 4; ++i) {
        int row = r + i * 16;
        float4 v = *(const float4*)(x + ((size_t)b * NN + n0 + row) * DD + d0 + c4);
        split_bf16(v.x, Th[row][c4 + 0], Tl[row][c4 + 0]);
        split_bf16(v.y, Th[row][c4 + 1], Tl[row][c4 + 1]);
        split_bf16(v.z, Th[row][c4 + 2], Tl[row][c4 + 2]);
        split_bf16(v.w, Th[row][c4 + 3], Tl[row][c4 + 3]);
    }
    __syncthreads();
    const int od = t >> 2;
    const int on0 = (t & 3) * 16;
    unsigned short hb[16], lb[16];
#pragma unroll
    for (int j = 0; j < 16; ++j) { hb[j] = Th[on0 + j][od]; lb[j] = Tl[on0 + j][od]; }
    const size_t obase = ((size_t)b * DD + d0 + od) * (size_t)NN + n0 + on0;
#pragma unroll
    for (int q = 0; q < 4; ++q) {
        ushort4 hv = {hb[q * 4 + 0], hb[q * 4 + 1], hb[q * 4 + 2], hb[q * 4 + 3]};
        ushort4 lv = {lb[q * 4 + 0], lb[q * 4 + 1], lb[q * 4 + 2], lb[q * 4 + 3]};
        *(ushort4*)(th + obase + q * 4) = hv;
        *(ushort4*)(tl + obase + q * 4) = lv;
    }
}

// ---------------- big GEMM: inter_slab = net_slab @ x  (split-3 bf16 MFMA)
// A planes: [2048][4096] (net slab, k contig). B planes: xT [b][512][4096] (k contig).
// Output: inter slab split planes [b*2048 + m][512].
__global__ __launch_bounds__(256, 2)
void gemm_big(const unsigned short* __restrict__ Ah, const unsigned short* __restrict__ Al,
              const unsigned short* __restrict__ Bh, const unsigned short* __restrict__ Bl,
              unsigned short* __restrict__ Ch, unsigned short* __restrict__ Cl)
{
    __shared__ alignas(16) unsigned short sAh[128 * 32];
    __shared__ alignas(16) unsigned short sAl[128 * 32];
    __shared__ alignas(16) unsigned short sBh[128 * 32];
    __shared__ alignas(16) unsigned short sBl[128 * 32];

    const int tid = threadIdx.x;
    const int lane = tid & 63;
    const int w = tid >> 6;

    const int n0 = blockIdx.x * 128;   // d tile (4)
    const int b  = blockIdx.y;         // batch (8)
    const int m0 = blockIdx.z * 128;   // local agent tile (16)

    Bh += (size_t)b * DD * NN;
    Bl += (size_t)b * DD * NN;

    const int c0 = w * 2, c1 = c0 + 1;
    const int u2 = lane >> 2;
    const int sst = (u2 + (u2 >> 2)) & 3;
    const int kc = (lane & 3) ^ sst;
    const size_t gA0 = (size_t)(m0 + c0 * 16 + u2) * NN + kc * 8;
    const size_t gA1 = (size_t)(m0 + c1 * 16 + u2) * NN + kc * 8;
    const size_t gB0 = (size_t)(n0 + c0 * 16 + u2) * NN + kc * 8;
    const size_t gB1 = (size_t)(n0 + c1 * 16 + u2) * NN + kc * 8;
    unsigned short* lAh0 = sAh + c0 * 512; unsigned short* lAh1 = sAh + c1 * 512;
    unsigned short* lAl0 = sAl + c0 * 512; unsigned short* lAl1 = sAl + c1 * 512;
    unsigned short* lBh0 = sBh + c0 * 512; unsigned short* lBh1 = sBh + c1 * 512;
    unsigned short* lBl0 = sBl + c0 * 512; unsigned short* lBl1 = sBl + c1 * 512;

    const int wm = (w & 1) * 64, wn = (w >> 1) * 64;
    const int fr = lane & 15;
    const int sf = (fr + (fr >> 2)) & 3;
    const int fslot = ((lane >> 4) ^ sf) * 16;
    int offA[4], offB[4];
#pragma unroll
    for (int i = 0; i < 4; ++i) {
        offA[i] = (wm + i * 16 + fr) * 64 + fslot;
        offB[i] = (wn + i * 16 + fr) * 64 + fslot;
    }

    f32x4 acc[4][4] = {};

    for (int kt = 0; kt < NN; kt += 32) {
        __syncthreads();
        gload_lds16(Ah + gA0 + kt, lAh0);
        gload_lds16(Ah + gA1 + kt, lAh1);
        gload_lds16(Al + gA0 + kt, lAl0);
        gload_lds16(Al + gA1 + kt, lAl1);
        gload_lds16(Bh + gB0 + kt, lBh0);
        gload_lds16(Bh + gB1 + kt, lBh1);
        gload_lds16(Bl + gB0 + kt, lBl0);
        gload_lds16(Bl + gB1 + kt, lBl1);
        asm volatile("s_waitcnt vmcnt(0)" ::: "memory");
        __syncthreads();

        bf16x8 ah[4], al[4], bh[4], bl[4];
#pragma unroll
        for (int i = 0; i < 4; ++i) {
            ah[i] = *(const bf16x8*)((const char*)sAh + offA[i]);
            al[i] = *(const bf16x8*)((const char*)sAl + offA[i]);
            bh[i] = *(const bf16x8*)((const char*)sBh + offB[i]);
            bl[i] = *(const bf16x8*)((const char*)sBl + offB[i]);
        }
#pragma unroll
        for (int mi = 0; mi < 4; ++mi)
#pragma unroll
            for (int ni = 0; ni < 4; ++ni) {
                acc[mi][ni] = __builtin_amdgcn_mfma_f32_16x16x32_bf16(al[mi], bh[ni], acc[mi][ni], 0, 0, 0);
                acc[mi][ni] = __builtin_amdgcn_mfma_f32_16x16x32_bf16(ah[mi], bl[ni], acc[mi][ni], 0, 0, 0);
                acc[mi][ni] = __builtin_amdgcn_mfma_f32_16x16x32_bf16(ah[mi], bh[ni], acc[mi][ni], 0, 0, 0);
            }
    }

    // epilogue: write inter slab as split bf16 planes. row = b*2048 + local m.
    const int erow = (lane >> 4) * 4;
#pragma unroll
    for (int mi = 0; mi < 4; ++mi)
#pragma unroll
        for (int ni = 0; ni < 4; ++ni) {
            const int r0 = m0 + wm + mi * 16 + erow;
            const int col = n0 + wn + ni * 16 + fr;
#pragma unroll
            for (int r = 0; r < 4; ++r) {
                unsigned short h, l;
                split_bf16(acc[mi][ni][r], h, l);
                const size_t idx = ((size_t)b * SLAB + r0 + r) * DD + col;
                Ch[idx] = h;
                Cl[idx] = l;
            }
        }
}

// ---------------- small GEMM: C[r][n] = sum_k A[r][k] * B[n][k] (+bias) (+C)
// A planes [16384][512] k-contig; B planes [512][512] k-contig; C fp32 [16384][512].
__global__ __launch_bounds__(256, 2)
void gemm_small(const unsigned short* __restrict__ Ah, const unsigned short* __restrict__ Al,
                const unsigned short* __restrict__ Bh, const unsigned short* __restrict__ Bl,
                const float* __restrict__ bias, float* __restrict__ C, int accum)
{
    __shared__ alignas(16) unsigned short sAh[128 * 32];
    __shared__ alignas(16) unsigned short sAl[128 * 32];
    __shared__ alignas(16) unsigned short sBh[128 * 32];
    __shared__ alignas(16) unsigned short sBl[128 * 32];

    const int tid = threadIdx.x;
    const int lane = tid & 63;
    const int w = tid >> 6;

    const int n0 = blockIdx.x * 128;   // 4 n-tiles
    const int m0 = blockIdx.y * 128;   // 128 m-tiles

    const int c0 = w * 2, c1 = c0 + 1;
    const int u2 = lane >> 2;
    const int sst = (u2 + (u2 >> 2)) & 3;
    const int kc = (lane & 3) ^ sst;
    const size_t gA0 = (size_t)(m0 + c0 * 16 + u2) * DD + kc * 8;
    const size_t gA1 = (size_t)(m0 + c1 * 16 + u2) * DD + kc * 8;
    const size_t gB0 = (size_t)(n0 + c0 * 16 + u2) * DD + kc * 8;
    const size_t gB1 = (size_t)(n0 + c1 * 16 + u2) * DD + kc * 8;
    unsigned short* lAh0 = sAh + c0 * 512; unsigned short* lAh1 = sAh + c1 * 512;
    unsigned short* lAl0 = sAl + c0 * 512; unsigned short* lAl1 = sAl + c1 * 512;
    unsigned short* lBh0 = sBh + c0 * 512; unsigned short* lBh1 = sBh + c1 * 512;
    unsigned short* lBl0 = sBl + c0 * 512; unsigned short* lBl1 = sBl + c1 * 512;

    const int wm = (w & 1) * 64, wn = (w >> 1) * 64;
    const int fr = lane & 15;
    const int sf = (fr + (fr >> 2)) & 3;
    const int fslot = ((lane >> 4) ^ sf) * 16;
    int offA[4], offB[4];
#pragma unroll
    for (int i = 0; i < 4; ++i) {
        offA[i] = (wm + i * 16 + fr) * 64 + fslot;
        offB[i] = (wn + i * 16 + fr) * 64 + fslot;
    }

    f32x4 acc[4][4] = {};

    for (int kt = 0; kt < DD; kt += 32) {
        __syncthreads();
        gload_lds16(Ah + gA0 + kt, lAh0);
        gload_lds16(Ah + gA1 + kt, lAh1);
        gload_lds16(Al + gA0 + kt, lAl0);
        gload_lds16(Al + gA1 + kt, lAl1);
        gload_lds16(Bh + gB0 + kt, lBh0);
        gload_lds16(Bh + gB1 + kt, lBh1);
        gload_lds16(Bl + gB0 + kt, lBl0);
        gload_lds16(Bl + gB1 + kt, lBl1);
        asm volatile("s_waitcnt vmcnt(0)" ::: "memory");
        __syncthreads();

        bf16x8 ah[4], al[4], bh[4], bl[4];
#pragma unroll
        for (int i = 0; i < 4; ++i) {
            ah[i] = *(const bf16x8*)((const char*)sAh + offA[i]);
            al[i] = *(const bf16x8*)((const char*)sAl + offA[i]);
            bh[i] = *(const bf16x8*)((const char*)sBh + offB[i]);
            bl[i] = *(const bf16x8*)((const char*)sBl + offB[i]);
        }
#pragma unroll
        for (int mi = 0; mi < 4; ++mi)
#pragma unroll
            for (int ni = 0; ni < 4; ++ni) {
                acc[mi][ni] = __builtin_amdgcn_mfma_f32_16x16x32_bf16(al[mi], bh[ni], acc[mi][ni], 0, 0, 0);
                acc[mi][ni] = __builtin_amdgcn_mfma_f32_16x16x32_bf16(ah[mi], bl[ni], acc[mi][ni], 0, 0, 0);
                acc[mi][ni] = __builtin_amdgcn_mfma_f32_16x16x32_bf16(ah[mi], bh[ni], acc[mi][ni], 0, 0, 0);
            }
    }

    const int erow = (lane >> 4) * 4;
#pragma unroll
    for (int mi = 0; mi < 4; ++mi)
#pragma unroll
        for (int ni = 0; ni < 4; ++ni) {
            const int r0 = m0 + wm + mi * 16 + erow;
            const int col = n0 + wn + ni * 16 + fr;
            const float bv = bias ? bias[col] : 0.0f;
#pragma unroll
            for (int r = 0; r < 4; ++r) {
                const size_t idx = (size_t)(r0 + r) * DD + col;
                float v = acc[mi][ni][r] + bv;
                if (accum) v += C[idx];
                C[idx] = v;
            }
        }
}

// ---------------- fused pointwise + LN + weighted accumulate (+energy at c==1)
__global__ __launch_bounds__(128)
void pw_slab(const float* __restrict__ x, const float* __restrict__ gp_,
             const float* __restrict__ cp_, const float* __restrict__ lg,
             const float* __restrict__ lb, const float* __restrict__ cmix,
             int c, int nbase, float* __restrict__ out, float* __restrict__ energy)
{
    __shared__ float sm[4];
    const int rloc = blockIdx.x;                       // 0..16383
    const int b = rloc >> 11, ii = rloc & (SLAB - 1);
    const int grow = (b << 12) + nbase + ii;           // global row
    const int tid = threadIdx.x;
    const size_t lbase = (size_t)rloc * DD + tid * 4;
    const size_t gbase = (size_t)grow * DD + tid * 4;

    float4 g4 = *(const float4*)(gp_ + lbase);
    float4 c4 = *(const float4*)(cp_ + lbase);
    float4 x4 = *(const float4*)(x + gbase);
    float gv[4] = {g4.x, g4.y, g4.z, g4.w};
    float cv[4] = {c4.x, c4.y, c4.z, c4.w};
    float xv[4] = {x4.x, x4.y, x4.z, x4.w};
    float h[4];
#pragma unroll
    for (int j = 0; j < 4; ++j) {
        float gate = 1.0f / (1.0f + expf(-gv[j]));
        float cand = 0.5f * cv[j] * (1.0f + erff(cv[j] * 0.70710678118654752440f));
        h[j] = gate * cand + (1.0f - gate) * xv[j];
    }

    const int lane = tid & 63, wid = tid >> 6;
    float s = h[0] + h[1] + h[2] + h[3];
#pragma unroll
    for (int off = 32; off > 0; off >>= 1) s += __shfl_xor(s, off, 64);
    if (lane == 0) sm[wid] = s;
    __syncthreads();
    float mu = (sm[0] + sm[1]) * (1.0f / 512.0f);
    float vs = 0.0f;
#pragma unroll
    for (int j = 0; j < 4; ++j) { float d = h[j] - mu; vs += d * d; }
#pragma unroll
    for (int off = 32; off > 0; off >>= 1) vs += __shfl_xor(vs, off, 64);
    if (lane == 0) sm[2 + wid] = vs;
    __syncthreads();
    float var = (sm[2] + sm[3]) * (1.0f / 512.0f);
    float rstd = 1.0f / sqrtf(var + 1e-5f);

    float m0 = cmix[0], m1 = cmix[1];
    float mx = fmaxf(m0, m1);
    float e0 = expf(m0 - mx), e1 = expf(m1 - mx);
    float wgt = ((c == 0) ? e0 : e1) / (e0 + e1);

    const int dix = tid * 4;
    float4 lg4 = *(const float4*)(lg + dix);
    float4 lb4 = *(const float4*)(lb + dix);
    float lgv[4] = {lg4.x, lg4.y, lg4.z, lg4.w};
    float lbv[4] = {lb4.x, lb4.y, lb4.z, lb4.w};
    float ov[4];
    if (c == 0) {
#pragma unroll
        for (int j = 0; j < 4; ++j)
            ov[j] = wgt * ((h[j] - mu) * rstd * lgv[j] + lbv[j]);
    } else {
        float4 o4 = *(const float4*)(out + gbase);
        ov[0] = o4.x; ov[1] = o4.y; ov[2] = o4.z; ov[3] = o4.w;
#pragma unroll
        for (int j = 0; j < 4; ++j)
            ov[j] += wgt * ((h[j] - mu) * rstd * lgv[j] + lbv[j]);
    }
    float4 st = {ov[0], ov[1], ov[2], ov[3]};
    *(float4*)(out + gbase) = st;

    if (c == 1) {
        // energy = ||out row||
        float s2 = ov[0] * ov[0] + ov[1] * ov[1] + ov[2] * ov[2] + ov[3] * ov[3];
#pragma unroll
        for (int off = 32; off > 0; off >>= 1) s2 += __shfl_xor(s2, off, 64);
        __syncthreads();
        if (lane == 0) sm[wid] = s2;
        __syncthreads();
        if (tid == 0) energy[grow] = sqrtf(sm[0] + sm[1]);
    }
}

// ---------------- per-batch top-k radix select; writes mask IN-PLACE over energy
__global__ __launch_bounds__(1024)
void topk_kernel(float* __restrict__ energy, const int* __restrict__ kptr)
{
    __shared__ unsigned keys[NN];
    __shared__ int hist[256];
    __shared__ int wsum[16];
    __shared__ unsigned sh_pfx;
    __shared__ int sh_need;

    const int b = blockIdx.x, tid = threadIdx.x;
    float* e = energy + (size_t)b * NN;
    for (int n = tid; n < NN; n += 1024) keys[n] = __float_as_uint(e[n]);
    const int K = *kptr;
    if (tid == 0) { sh_pfx = 0u; sh_need = K; }
    __syncthreads();

    for (int round = 0; round < 4; ++round) {
        const int shift = 24 - 8 * round;
        if (tid < 256) hist[tid] = 0;
        __syncthreads();
        const unsigned pfx = sh_pfx;
        const unsigned mhi = (round == 0) ? 0u : (0xFFFFFFFFu << (shift + 8));
        for (int n = tid; n < NN; n += 1024) {
            unsigned kv = keys[n];
            if ((kv & mhi) == pfx) atomicAdd(&hist[(kv >> shift) & 255], 1);
        }
        __syncthreads();
        if (tid == 0) {
            int need = sh_need;
            int d = 255;
            for (;; --d) {
                int cct = hist[d];
                if (need <= cct) break;
                need -= cct;
            }
            sh_pfx = pfx | ((unsigned)d << shift);
            sh_need = need;
        }
        __syncthreads();
    }

    const unsigned T = sh_pfx;
    const int need = sh_need;

    const int n0 = tid * 4;
    unsigned kv[4]; int eq[4]; int loc[4];
    int s = 0;
#pragma unroll
    for (int j = 0; j < 4; ++j) {
        kv[j] = keys[n0 + j];
        eq[j] = (kv[j] == T) ? 1 : 0;
        loc[j] = s; s += eq[j];
    }
    const int lane = tid & 63, wid = tid >> 6;
    int v = s;
#pragma unroll
    for (int off = 1; off < 64; off <<= 1) {
        int u = __shfl_up(v, off, 64);
        if (lane >= off) v += u;
    }
    if (lane == 63) wsum[wid] = v;
    __syncthreads();
    if (tid == 0) {
        int acc = 0;
        for (int w2 = 0; w2 < 16; ++w2) { int t = wsum[w2]; wsum[w2] = acc; acc += t; }
    }
    __syncthreads();
    const int base = wsum[wid] + (v - s);
    const float scale = (float)(4096.0 / (double)K);
#pragma unroll
    for (int j = 0; j < 4; ++j) {
        bool sel = (kv[j] > T) || (eq[j] && (base + loc[j]) < need);
        e[n0 + j] = sel ? scale : 0.0f;
    }
}

__global__ __launch_bounds__(128)
void mask_kernel(float* __restrict__ out, const float* __restrict__ mscale)
{
    const int row = blockIdx.x;
    const int tid = threadIdx.x;
    const size_t base = (size_t)row * DD + tid * 4;
    const float sc = mscale[row];
    float4 v = *(const float4*)(out + base);
    v.x *= sc; v.y *= sc; v.z *= sc; v.w *= sc;
    *(float4*)(out + base) = v;
}

extern "C" void kernel_launch(void* const* d_in, const int* in_sizes, int n_in,
                              void* d_out, int out_size, void* d_ws, size_t ws_size,
                              hipStream_t stream)
{
    const float* x      = (const float*)d_in[0];
    const float* net    = (const float*)d_in[1];
    const float* gate_w = (const float*)d_in[2];
    const float* gate_b = (const float*)d_in[3];
    const float* cand_w = (const float*)d_in[4];
    const float* cand_b = (const float*)d_in[5];
    const float* ln_g   = (const float*)d_in[6];
    const float* ln_b   = (const float*)d_in[7];
    const float* cmix   = (const float*)d_in[8];
    const int*   kptr   = (const int*)d_in[9];
    float* out = (float*)d_out;

    const size_t ROWS  = (size_t)BB * NN;      // 32768
    const size_t PLANE = ROWS * DD;            // 16,777,216 elems

    // Workspace carve — total 201,457,664 B (<= proven 201,588,736):
    //   Slot A: xT hi/lo bf16 [b][d][n]                 67,108,864
    //   Slot N: net slab split (2048x4096 hi+lo)        33,554,432
    //           (reused for weight splits after gemm_big frees it)
    //   Slot I: inter slab split [16384][512] hi+lo     33,554,432
    //   Slot X: x slab split hi+lo -> candp fp32        33,554,432
    //   Slot G: gatep fp32 [16384][512]                 33,554,432
    //   energy [32768] fp32 (topk writes mask in-place)    131,072
    char* p = (char*)d_ws;
    unsigned short* xTh = (unsigned short*)p;             p += PLANE * 2;
    unsigned short* xTl = (unsigned short*)p;             p += PLANE * 2;
    char* slotN = p;                                      p += (size_t)SLAB * NN * 2 * 2;
    unsigned short* netsh = (unsigned short*)slotN;
    unsigned short* netsl = netsh + (size_t)SLAB * NN;
    unsigned short* cwh = (unsigned short*)slotN;          // weight aliases (post-gemm_big)
    unsigned short* cwl = cwh + 512 * 512;
    unsigned short* gxh = cwl + 512 * 512;
    unsigned short* gxl = gxh + 512 * 512;
    unsigned short* gih = gxl + 512 * 512;
    unsigned short* gil = gih + 512 * 512;
    unsigned short* inth = (unsigned short*)p;            p += (size_t)SROWS * DD * 2;
    unsigned short* intl = (unsigned short*)p;            p += (size_t)SROWS * DD * 2;
    char* slotX = p;                                      p += (size_t)SROWS * DD * 4;
    unsigned short* xsh = (unsigned short*)slotX;
    unsigned short* xsl = xsh + (size_t)SROWS * DD;
    float* candp = (float*)slotX;                         // alias (post-gate0)
    float* gatep = (float*)p;                             p += (size_t)SROWS * DD * 4;
    float* energy = (float*)p;

    // x -> transposed split planes (once)
    conv_xT<<<dim3(NN / 64, DD / 64, BB), 256, 0, stream>>>(x, xTh, xTl);

    for (int c = 0; c < 2; ++c) {
        for (int s = 0; s < 2; ++s) {
            const int nbase = s * SLAB;
            // net slab -> split planes
            conv_split<<<(SLAB * NN / 4) / 256, 256, 0, stream>>>(
                net + (size_t)c * NN * NN + (size_t)nbase * NN, netsh, netsl);
            // inter slab = net_slab @ x   (split-3 MFMA)
            gemm_big<<<dim3(DD / 128, BB, SLAB / 128), 256, 0, stream>>>(
                netsh, netsl, xTh, xTl, inth, intl);
            // weights -> split planes (into slot N, now free)
            conv_w3<<<768, 256, 0, stream>>>(
                cand_w + (size_t)c * DD * DD, gate_w + (size_t)c * DD * 2 * DD,
                cwh, cwl, gxh, gxl, gih, gil);
            // x slab -> split planes
            conv_xs<<<(SROWS * DD / 4) / 256, 256, 0, stream>>>(x, nbase, xsh, xsl);
            // gate_pre = x @ gwx^T + gate_b
            gemm_small<<<dim3(4, SROWS / 128), 256, 0, stream>>>(
                xsh, xsl, gxh, gxl, gate_b + (size_t)c * DD, gatep, 0);
            // cand_pre = inter @ cw^T + cand_b   (overwrites x slab slot)
            gemm_small<<<dim3(4, SROWS / 128), 256, 0, stream>>>(
                inth, intl, cwh, cwl, cand_b + (size_t)c * DD, candp, 0);
            // gate_pre += inter @ gwi^T
            gemm_small<<<dim3(4, SROWS / 128), 256, 0, stream>>>(
                inth, intl, gih, gil, nullptr, gatep, 1);
            // pointwise + LN + accumulate (+energy at c==1)
            pw_slab<<<SROWS, 128, 0, stream>>>(
                x, gatep, candp, ln_g + (size_t)c * DD, ln_b + (size_t)c * DD,
                cmix, c, nbase, out, energy);
        }
    }

    topk_kernel<<<BB, 1024, 0, stream>>>(energy, kptr);
    mask_kernel<<<(int)ROWS, 128, 0, stream>>>(out, energy);
}